// Round 16
// baseline (233.012 us; speedup 1.0000x reference)
//
#include <hip/hip_runtime.h>

#define NN 100000
#define NE 1600000
#define NF 128
#define NH 256
#define NC 47
#define NB 391            // ceil(NN/256) buckets of 256 nodes
#define CH 8192           // edges per chunk
#define NCH ((NE + CH - 1) / CH)   // 196

// prep_k block-role offsets
#define PB_HIST 0
#define PB_CAST (PB_HIST + NCH)                  // 196
#define NCAST   (NN * NF / 4 / 256)              // 12500
#define PB_BT1  (PB_CAST + NCAST)                // 12696
#define PB_BT2  (PB_BT1 + 256)                   // 12952
#define PB_END  (PB_BT2 + 96)                    // 13048

typedef __attribute__((ext_vector_type(8))) short bf16x8;
typedef __attribute__((ext_vector_type(4))) float f32x4;
typedef __attribute__((ext_vector_type(2))) float f32x2;

typedef __attribute__((address_space(1))) const void as1_void;
typedef __attribute__((address_space(3))) void as3_void;
__device__ __forceinline__ void gload16(const void* g, void* l) {
    __builtin_amdgcn_global_load_lds((as1_void*)g, (as3_void*)l, 16, 0, 0);
}

__device__ inline unsigned short f2bf(float f) {
    unsigned u = __builtin_bit_cast(unsigned, f);
    unsigned r = u + 0x7fffu + ((u >> 16) & 1u);
    return (unsigned short)(r >> 16);
}
__device__ inline float bfl(unsigned u) {
    return __builtin_bit_cast(float, u << 16);
}

// ---------------- fused prep: chunk_hist | cast_x (bf16 + fp8) | prep_bt1 | prep_bt2 ----------------

__global__ __launch_bounds__(256) void prep_k(const int* __restrict__ dst,
                                              int* __restrict__ chunk_hist,
                                              int* __restrict__ total,
                                              const float* __restrict__ x,
                                              unsigned short* __restrict__ xb,
                                              unsigned* __restrict__ xq,
                                              const float* __restrict__ Wl1,
                                              const float* __restrict__ Wr1,
                                              unsigned short* __restrict__ Bt1,
                                              const float* __restrict__ Wl2,
                                              const float* __restrict__ Wr2,
                                              unsigned short* __restrict__ Bt2) {
    __shared__ int h[NB];
    int tid = threadIdx.x;
    int blk = blockIdx.x;
    if (blk < PB_CAST) {                       // chunk histogram
        int ch = blk;
        for (int i = tid; i < NB; i += 256) h[i] = 0;
        __syncthreads();
        int e0 = ch * CH;
        int e1 = min(e0 + CH, NE);
        for (int e = e0 + tid; e < e1; e += 256)
            atomicAdd(&h[dst[e] >> 8], 1);
        __syncthreads();
        for (int i = tid; i < NB; i += 256) {
            int v = h[i];
            chunk_hist[(size_t)ch * NB + i] = v;
            if (v) atomicAdd(&total[i], v);
        }
    } else if (blk < PB_BT1) {                 // cast x -> bf16 + fp8
        int i = (blk - PB_CAST) * 256 + tid;
        float4 v = *reinterpret_cast<const float4*>(x + (size_t)i * 4);
        ushort4 o;
        o.x = f2bf(v.x); o.y = f2bf(v.y); o.z = f2bf(v.z); o.w = f2bf(v.w);
        *reinterpret_cast<ushort4*>(xb + (size_t)i * 4) = o;
        int r = __builtin_amdgcn_cvt_pk_fp8_f32(v.x, v.y, 0, false);
        r = __builtin_amdgcn_cvt_pk_fp8_f32(v.z, v.w, r, true);
        xq[i] = (unsigned)r;
    } else if (blk < PB_BT2) {                 // Bt1[n][k]
        int idx = (blk - PB_BT1) * 256 + tid;
        int n = idx >> 8, k = idx & 255;
        float v = (k < 128) ? Wl1[(size_t)k * NH + n] : Wr1[(size_t)(k - 128) * NH + n];
        Bt1[idx] = f2bf(v);
    } else {                                   // Bt2[n][k]
        int idx = (blk - PB_BT2) * 256 + tid;
        int n = idx >> 8, k = idx & 255;
        float v = 0.f;
        if (n < 47) v = Wl2[(size_t)k * NC + n];
        else if (n >= 48 && n < 95) v = Wr2[(size_t)k * NC + (n - 48)];
        Bt2[idx] = f2bf(v);
    }
}

// ---------------- fused scan + per-bucket column scan ----------------

__global__ __launch_bounds__(64) void scancol_k(const int* __restrict__ chunk_hist,
                                                const int* __restrict__ total,
                                                int* __restrict__ bucket_base,
                                                int* __restrict__ chunk_off) {
    int b = blockIdx.x;
    int lane = threadIdx.x;
    int base = 0;
    for (int i0 = 0; i0 < NB; i0 += 64) {
        int i = i0 + lane;
        base += (i < b) ? total[i] : 0;
    }
    #pragma unroll
    for (int off = 1; off < 64; off <<= 1)
        base += __shfl_xor(base, off);
    if (lane == 0) bucket_base[b] = base;
    int run = base;
    for (int c0 = 0; c0 < NCH; c0 += 64) {
        int c = c0 + lane;
        int v = (c < NCH) ? chunk_hist[(size_t)c * NB + b] : 0;
        int s = v;
        #pragma unroll
        for (int off = 1; off < 64; off <<= 1) {
            int t = __shfl_up(s, off);
            if (lane >= off) s += t;
        }
        if (c < NCH) chunk_off[(size_t)c * NB + b] = run + s - v;
        run += __shfl(s, 63);
    }
}

__global__ __launch_bounds__(256) void scatter2_k(const int* __restrict__ src,
                                                  const int* __restrict__ dst,
                                                  const int* __restrict__ chunk_off,
                                                  unsigned* __restrict__ ebuf) {
    __shared__ int cur[NB];
    int tid = threadIdx.x, ch = blockIdx.x;
    for (int i = tid; i < NB; i += 256)
        cur[i] = chunk_off[(size_t)ch * NB + i];
    __syncthreads();
    int e0 = ch * CH;
    int e1 = min(e0 + CH, NE);
    for (int e = e0 + tid; e < e1; e += 256) {
        int d = dst[e];
        int b = d >> 8;
        int p = atomicAdd(&cur[b], 1);
        ebuf[p] = ((unsigned)(d & 255) << 24) | (unsigned)src[e];
    }
}

__global__ __launch_bounds__(256) void build_csr_k(const unsigned* __restrict__ ebuf,
                                                   const int* __restrict__ bucket_base,
                                                   const int* __restrict__ bucket_cnt,
                                                   int* __restrict__ row_start,
                                                   int* __restrict__ deg,
                                                   float* __restrict__ inv_deg,
                                                   int* __restrict__ csr_src) {
    __shared__ int s[256];
    __shared__ int cursor[256];
    int tid = threadIdx.x;
    int b = blockIdx.x;
    int lo = b << 8;
    int ebase = bucket_base[b];
    int ne = bucket_cnt[b];

    s[tid] = 0;
    __syncthreads();
    for (int e = tid; e < ne; e += 256)
        atomicAdd(&s[ebuf[ebase + e] >> 24], 1);
    __syncthreads();
    int v = s[tid];
    __syncthreads();
    for (int off = 1; off < 256; off <<= 1) {
        int t = (tid >= off) ? s[tid - off] : 0;
        __syncthreads();
        s[tid] += t;
        __syncthreads();
    }
    int excl = s[tid] - v;
    int node = lo + tid;
    if (node < NN) {
        row_start[node] = ebase + excl;
        deg[node] = v;
        inv_deg[node] = 1.0f / (float)(v > 1 ? v : 1);
    }
    cursor[tid] = ebase + excl;
    __syncthreads();
    for (int e = tid; e < ne; e += 256) {
        unsigned u = ebuf[ebase + e];
        int p = atomicAdd(&cursor[u >> 24], 1);
        csr_src[p] = (int)(u & 0xFFFFFFu);
    }
}

// ---------------- agg47: node per 16-lane group, 8 rows in flight per group ----------------

// fp8 t-gather: row = 64B = 16 lanes x dword.
__global__ __launch_bounds__(256) void agg_mean_47q_add_k(const unsigned* __restrict__ tq,
                                                          const int* __restrict__ csr_src,
                                                          const int* __restrict__ row_start,
                                                          const int* __restrict__ deg,
                                                          const float* __restrict__ inv_deg,
                                                          float* __restrict__ out) {
    int node = blockIdx.x * 16 + (threadIdx.x >> 4);
    int l16 = threadIdx.x & 15;
    if (node >= NN) return;
    int s0 = row_start[node];
    int d  = deg[node];
    f32x2 a01 = {0.f, 0.f}, a23 = {0.f, 0.f};
    int j = 0;
    for (; j + 7 < d; j += 8) {
        unsigned w[8];
        #pragma unroll
        for (int r = 0; r < 8; ++r) {
            int s = csr_src[s0 + j + r];
            w[r] = tq[(size_t)s * 16 + l16];
        }
        #pragma unroll
        for (int r = 0; r < 8; ++r) {
            a01 += __builtin_amdgcn_cvt_pk_f32_fp8((int)w[r], false);
            a23 += __builtin_amdgcn_cvt_pk_f32_fp8((int)w[r], true);
        }
    }
    for (; j + 3 < d; j += 4) {
        unsigned w[4];
        #pragma unroll
        for (int r = 0; r < 4; ++r) {
            int s = csr_src[s0 + j + r];
            w[r] = tq[(size_t)s * 16 + l16];
        }
        #pragma unroll
        for (int r = 0; r < 4; ++r) {
            a01 += __builtin_amdgcn_cvt_pk_f32_fp8((int)w[r], false);
            a23 += __builtin_amdgcn_cvt_pk_f32_fp8((int)w[r], true);
        }
    }
    for (; j < d; ++j) {
        int s = csr_src[s0 + j];
        unsigned w = tq[(size_t)s * 16 + l16];
        a01 += __builtin_amdgcn_cvt_pk_f32_fp8((int)w, false);
        a23 += __builtin_amdgcn_cvt_pk_f32_fp8((int)w, true);
    }
    float inv = inv_deg[node];
    int c0 = l16 * 4;
    float vals[4] = {a01.x, a01.y, a23.x, a23.y};
    #pragma unroll
    for (int m = 0; m < 4; ++m) {
        int col = c0 + m;
        if (col < NC) {
            size_t o = (size_t)node * NC + col;
            out[o] += vals[m] * inv;
        }
    }
}

// ---------------- fused GEMM12F: gather(mean) + gemm1 + gemm2 in one kernel ----------------
// BM=64, 256 thr (4 waves). Phase 0: stage A-xb half (gload_lds, issued first) while
// 16-lane groups gather the fp8 mean for the block's 64 nodes into swizzled LDS A-tiles
// (mean1 buffer eliminated). gemm1: A fully LDS-resident, B 2-buffer staged.
// gemm2: A from Hs, B from L2-hot Bt2. LDS union = (Am16+Axb16+Bs32) | Hs32 = 64 KB -> 2 blocks/CU.

__global__ __launch_bounds__(256, 2) void gemm12f_k(const unsigned* __restrict__ xq,
                                                    const unsigned short* __restrict__ xb,
                                                    const int* __restrict__ csr_src,
                                                    const int* __restrict__ row_start,
                                                    const int* __restrict__ deg,
                                                    const float* __restrict__ inv_deg,
                                                    const unsigned short* __restrict__ Bt1,
                                                    const float* __restrict__ b1,
                                                    const unsigned short* __restrict__ Bt2,
                                                    const float* __restrict__ b2,
                                                    unsigned char* __restrict__ tq,
                                                    float* __restrict__ out) {
    __shared__ __align__(16) union SM {
        struct { short Am[4][64 * 32]; short Axb[4][64 * 32]; short Bs[2][256 * 32]; } g; // 64 KB
        unsigned short Hs[64 * 256];                                                       // 32 KB
    } sm;
    const int tid = threadIdx.x;
    const int row0 = blockIdx.x * 64;
    const int lane = tid & 63;
    const int wid = tid >> 6;                    // 0..3
    const int r15 = lane & 15;
    const int kg = lane >> 4;                    // 0..3
    const int swz = (kg ^ ((lane >> 1) & 3)) & 3;

    // ---- phase 0a: stage A-xb half (4 tiles of [64][32]), issued early ----
    {
        int row = tid >> 2, g = tid & 3;
        int grow = row0 + row;
        if (grow >= NN) grow = NN - 1;           // clamp; outputs guarded later
        int gs = g ^ ((row >> 1) & 3);
        #pragma unroll
        for (int ts = 0; ts < 4; ++ts)
            gload16(xb + (size_t)grow * NF + ts * 32 + gs * 8, &sm.g.Axb[ts][tid * 8]);
    }

    // ---- phase 0b: gather fp8 mean for 64 nodes -> Am (swizzled bf16) ----
    {
        int grp = tid >> 4, l16 = tid & 15;
        #pragma unroll 1
        for (int it = 0; it < 4; ++it) {
            int nl = grp + it * 16;              // 0..63
            int node = row0 + nl;
            f32x2 acc[4];
            #pragma unroll
            for (int k = 0; k < 4; ++k) acc[k] = f32x2{0.f, 0.f};
            float inv = 0.f;
            if (node < NN) {
                int s0 = row_start[node];
                int d  = deg[node];
                int j = 0;
                for (; j + 7 < d; j += 8) {
                    uint2 w[8];
                    #pragma unroll
                    for (int r = 0; r < 8; ++r) {
                        int s = csr_src[s0 + j + r];
                        w[r] = *reinterpret_cast<const uint2*>(xq + (size_t)s * 32 + l16 * 2);
                    }
                    #pragma unroll
                    for (int r = 0; r < 8; ++r) {
                        acc[0] += __builtin_amdgcn_cvt_pk_f32_fp8((int)w[r].x, false);
                        acc[1] += __builtin_amdgcn_cvt_pk_f32_fp8((int)w[r].x, true);
                        acc[2] += __builtin_amdgcn_cvt_pk_f32_fp8((int)w[r].y, false);
                        acc[3] += __builtin_amdgcn_cvt_pk_f32_fp8((int)w[r].y, true);
                    }
                }
                for (; j + 3 < d; j += 4) {
                    uint2 w[4];
                    #pragma unroll
                    for (int r = 0; r < 4; ++r) {
                        int s = csr_src[s0 + j + r];
                        w[r] = *reinterpret_cast<const uint2*>(xq + (size_t)s * 32 + l16 * 2);
                    }
                    #pragma unroll
                    for (int r = 0; r < 4; ++r) {
                        acc[0] += __builtin_amdgcn_cvt_pk_f32_fp8((int)w[r].x, false);
                        acc[1] += __builtin_amdgcn_cvt_pk_f32_fp8((int)w[r].x, true);
                        acc[2] += __builtin_amdgcn_cvt_pk_f32_fp8((int)w[r].y, false);
                        acc[3] += __builtin_amdgcn_cvt_pk_f32_fp8((int)w[r].y, true);
                    }
                }
                for (; j < d; ++j) {
                    int s = csr_src[s0 + j];
                    uint2 w = *reinterpret_cast<const uint2*>(xq + (size_t)s * 32 + l16 * 2);
                    acc[0] += __builtin_amdgcn_cvt_pk_f32_fp8((int)w.x, false);
                    acc[1] += __builtin_amdgcn_cvt_pk_f32_fp8((int)w.x, true);
                    acc[2] += __builtin_amdgcn_cvt_pk_f32_fp8((int)w.y, false);
                    acc[3] += __builtin_amdgcn_cvt_pk_f32_fp8((int)w.y, true);
                }
                inv = inv_deg[node];
            }
            bf16x8 o;
            #pragma unroll
            for (int k = 0; k < 4; ++k) {
                o[k * 2]     = (short)f2bf(acc[k].x * inv);
                o[k * 2 + 1] = (short)f2bf(acc[k].y * inv);
            }
            // lane l16 holds k-chunk l16: tile ts = l16>>2, group g = l16&3
            int ts = l16 >> 2, g = l16 & 3;
            int slot = g ^ ((nl >> 1) & 3);
            *reinterpret_cast<bf16x8*>(&sm.g.Am[ts][nl * 32 + slot * 8]) = o;
        }
    }
    __syncthreads();   // Am written, Axb loads drained

    // ---- gemm1: wave wc=wid covers cols wc*64..+63; A resident, B 2-buffer ----
    const int wc = wid;
    f32x4 acc1[4][4];
    #pragma unroll
    for (int i = 0; i < 4; ++i)
        #pragma unroll
        for (int j = 0; j < 4; ++j)
            acc1[i][j] = f32x4{0.f, 0.f, 0.f, 0.f};

    auto stageB = [&](int buf, int kt) {
        #pragma unroll
        for (int i = 0; i < 4; ++i) {            // B: 256 rows x 4 groups = 1024 chunks
            int c = tid + i * 256;
            int rn = c >> 2, g = c & 3;
            int gs = g ^ ((rn >> 1) & 3);
            gload16(Bt1 + (size_t)rn * 256 + kt + gs * 8, &sm.g.Bs[buf][c * 8]);
        }
    };
    auto compute = [&](int buf, int kt) {
        const short* Abase = (kt < 128) ? sm.g.Am[kt >> 5] : sm.g.Axb[(kt - 128) >> 5];
        bf16x8 a[4], b[4];
        #pragma unroll
        for (int mi = 0; mi < 4; ++mi)
            a[mi] = *reinterpret_cast<const bf16x8*>(&Abase[(mi * 16 + r15) * 32 + swz * 8]);
        #pragma unroll
        for (int ni = 0; ni < 4; ++ni)
            b[ni] = *reinterpret_cast<const bf16x8*>(&sm.g.Bs[buf][(wc * 64 + ni * 16 + r15) * 32 + swz * 8]);
        #pragma unroll
        for (int mi = 0; mi < 4; ++mi)
            #pragma unroll
            for (int ni = 0; ni < 4; ++ni)
                acc1[mi][ni] = __builtin_amdgcn_mfma_f32_16x16x32_bf16(a[mi], b[ni], acc1[mi][ni], 0, 0, 0);
    };

    stageB(0, 0);
    __syncthreads();
    int cur = 0;
    #pragma unroll 1
    for (int ks = 0; ks < 8; ++ks) {
        if (ks + 1 < 8) stageB(cur ^ 1, (ks + 1) * 32);
        compute(cur, ks * 32);
        __syncthreads();
        cur ^= 1;
    }
    // Am/Axb/Bs dead -> Hs overwrite safe

    // h -> LDS (relu+bias, bf16, swizzled)
    #pragma unroll
    for (int ni = 0; ni < 4; ++ni) {
        int col = wc * 64 + ni * 16 + r15;
        float bias = b1[col];
        int kgrp = col >> 3, within = col & 7;
        #pragma unroll
        for (int mi = 0; mi < 4; ++mi) {
            int rbase = mi * 16 + kg * 4;
            f32x4 c = acc1[mi][ni];
            #pragma unroll
            for (int q = 0; q < 4; ++q) {
                int row = rbase + q;
                float v = fmaxf(c[q] + bias, 0.f);
                sm.Hs[row * 256 + (kgrp ^ (row & 31)) * 8 + within] = f2bf(v);
            }
        }
    }
    __syncthreads();

    // ---- gemm2: waves 2x2 (rows 32, cols 48 each); A from Hs, B from Bt2 ----
    const int wr2 = wid >> 1, wc2 = wid & 1;
    f32x4 acc2[2][3];
    #pragma unroll
    for (int i = 0; i < 2; ++i)
        #pragma unroll
        for (int j = 0; j < 3; ++j)
            acc2[i][j] = f32x4{0.f, 0.f, 0.f, 0.f};

    #pragma unroll
    for (int kt = 0; kt < 256; kt += 32) {
        bf16x8 a2[2], b2f[3];
        #pragma unroll
        for (int mi = 0; mi < 2; ++mi) {
            int row = wr2 * 32 + mi * 16 + r15;
            int kgrp = (kt >> 3) + kg;
            a2[mi] = *reinterpret_cast<const bf16x8*>(&sm.Hs[row * 256 + (kgrp ^ (row & 31)) * 8]);
        }
        #pragma unroll
        for (int ni = 0; ni < 3; ++ni) {
            int n = wc2 * 48 + ni * 16 + r15;
            b2f[ni] = *reinterpret_cast<const bf16x8*>(Bt2 + (size_t)n * 256 + kt + kg * 8);
        }
        #pragma unroll
        for (int mi = 0; mi < 2; ++mi)
            #pragma unroll
            for (int ni = 0; ni < 3; ++ni)
                acc2[mi][ni] = __builtin_amdgcn_mfma_f32_16x16x32_bf16(a2[mi], b2f[ni], acc2[mi][ni], 0, 0, 0);
    }

    #pragma unroll
    for (int ni = 0; ni < 3; ++ni) {
        int col = wc2 * 48 + ni * 16 + r15;      // 0..95
        float bias = (col >= 48 && col < 95) ? b2[col - 48] : 0.f;
        #pragma unroll
        for (int mi = 0; mi < 2; ++mi) {
            int rbase = row0 + wr2 * 32 + mi * 16 + kg * 4;
            f32x4 c = acc2[mi][ni];
            #pragma unroll
            for (int q = 0; q < 4; ++q) {
                int row = rbase + q;
                if (row < NN) {
                    if (col < 47) {
                        int p = __builtin_amdgcn_cvt_pk_fp8_f32(c[q], c[q], 0, false);
                        tq[(size_t)row * 64 + col] = (unsigned char)(p & 0xFF);
                    } else if (col >= 48 && col < 95) {
                        out[(size_t)row * NC + (col - 48)] = c[q] + bias;
                    }
                }
            }
        }
    }
}

// ---------------- launch ----------------

extern "C" void kernel_launch(void* const* d_in, const int* in_sizes, int n_in,
                              void* d_out, int out_size, void* d_ws, size_t ws_size,
                              hipStream_t stream) {
    const float* x    = (const float*)d_in[0];
    const int*   eidx = (const int*)d_in[1];
    const float* Wl1  = (const float*)d_in[2];
    const float* Wr1  = (const float*)d_in[3];
    const float* b1   = (const float*)d_in[4];
    const float* Wl2  = (const float*)d_in[5];
    const float* Wr2  = (const float*)d_in[6];
    const float* b2   = (const float*)d_in[7];
    float* out = (float*)d_out;

    const int* src = eidx;
    const int* dst = eidx + NE;

    size_t off = 0;
    auto alloc = [&](size_t bytes) -> void* {
        void* p = (char*)d_ws + off;
        off += (bytes + 511) & ~(size_t)511;
        return p;
    };
    int*            deg        = (int*)alloc((size_t)NN * 4);
    int*            row_start  = (int*)alloc((size_t)NN * 4);
    float*          inv_deg    = (float*)alloc((size_t)NN * 4);
    int*            csr_src    = (int*)alloc((size_t)NE * 4);
    unsigned*       ebuf       = (unsigned*)alloc((size_t)NE * 4);
    int*            chunk_hist = (int*)alloc((size_t)NCH * NB * 4);
    int*            chunk_off  = (int*)alloc((size_t)NCH * NB * 4);
    int*            bkt_cnt    = (int*)alloc((size_t)NB * 4);
    int*            bkt_base   = (int*)alloc((size_t)NB * 4);
    unsigned short* xb         = (unsigned short*)alloc((size_t)NN * NF * 2);
    unsigned*       xq         = (unsigned*)alloc((size_t)NN * NF);       // fp8 x, 32 words/row
    unsigned char*  tq         = (unsigned char*)alloc((size_t)NN * 64);  // fp8 t, 64B rows
    unsigned short* Bt1        = (unsigned short*)alloc((size_t)256 * 256 * 2);
    unsigned short* Bt2        = (unsigned short*)alloc((size_t)96 * 256 * 2);
    (void)ws_size; (void)n_in; (void)in_sizes; (void)out_size;

    hipMemsetAsync(bkt_cnt, 0, (size_t)NB * 4, stream);
    prep_k<<<PB_END, 256, 0, stream>>>(dst, chunk_hist, bkt_cnt,
                                       x, xb, xq, Wl1, Wr1, Bt1, Wl2, Wr2, Bt2);
    scancol_k<<<NB, 64, 0, stream>>>(chunk_hist, bkt_cnt, bkt_base, chunk_off);
    scatter2_k<<<NCH, 256, 0, stream>>>(src, dst, chunk_off, ebuf);
    build_csr_k<<<NB, 256, 0, stream>>>(ebuf, bkt_base, bkt_cnt,
                                        row_start, deg, inv_deg, csr_src);

    gemm12f_k<<<(NN + 63) / 64, 256, 0, stream>>>(xq, xb, csr_src, row_start, deg, inv_deg,
                                                  Bt1, b1, Bt2, b2, tq, out);

    agg_mean_47q_add_k<<<(NN + 15) / 16, 256, 0, stream>>>((const unsigned*)tq, csr_src, row_start, deg, inv_deg, out);
}

// Round 17
// 184.393 us; speedup vs baseline: 1.2637x; 1.2637x over previous
//
#include <hip/hip_runtime.h>

#define NN 100000
#define NE 1600000
#define NF 128
#define NH 256
#define NC 47
#define NB 391            // ceil(NN/256) buckets of 256 nodes
#define CH 8192           // edges per chunk
#define NCH ((NE + CH - 1) / CH)   // 196

// prep_k block-role offsets
#define PB_HIST 0
#define PB_CAST (PB_HIST + NCH)                  // 196
#define NCAST   (NN * NF / 4 / 256)              // 12500
#define PB_BT1  (PB_CAST + NCAST)                // 12696
#define PB_BT2  (PB_BT1 + 256)                   // 12952
#define PB_END  (PB_BT2 + 96)                    // 13048

typedef __attribute__((ext_vector_type(8))) short bf16x8;
typedef __attribute__((ext_vector_type(4))) float f32x4;
typedef __attribute__((ext_vector_type(2))) float f32x2;

typedef __attribute__((address_space(1))) const void as1_void;
typedef __attribute__((address_space(3))) void as3_void;
__device__ __forceinline__ void gload16(const void* g, void* l) {
    __builtin_amdgcn_global_load_lds((as1_void*)g, (as3_void*)l, 16, 0, 0);
}

__device__ inline unsigned short f2bf(float f) {
    unsigned u = __builtin_bit_cast(unsigned, f);
    unsigned r = u + 0x7fffu + ((u >> 16) & 1u);
    return (unsigned short)(r >> 16);
}
__device__ inline float bfl(unsigned u) {
    return __builtin_bit_cast(float, u << 16);
}

// ---------------- fused prep: chunk_hist | cast_x (bf16 + fp8) | prep_bt1 | prep_bt2 ----------------

__global__ __launch_bounds__(256) void prep_k(const int* __restrict__ dst,
                                              int* __restrict__ chunk_hist,
                                              int* __restrict__ total,
                                              const float* __restrict__ x,
                                              unsigned short* __restrict__ xb,
                                              unsigned* __restrict__ xq,
                                              const float* __restrict__ Wl1,
                                              const float* __restrict__ Wr1,
                                              unsigned short* __restrict__ Bt1,
                                              const float* __restrict__ Wl2,
                                              const float* __restrict__ Wr2,
                                              unsigned short* __restrict__ Bt2) {
    __shared__ int h[NB];
    int tid = threadIdx.x;
    int blk = blockIdx.x;
    if (blk < PB_CAST) {                       // chunk histogram
        int ch = blk;
        for (int i = tid; i < NB; i += 256) h[i] = 0;
        __syncthreads();
        int e0 = ch * CH;
        int e1 = min(e0 + CH, NE);
        for (int e = e0 + tid; e < e1; e += 256)
            atomicAdd(&h[dst[e] >> 8], 1);
        __syncthreads();
        for (int i = tid; i < NB; i += 256) {
            int v = h[i];
            chunk_hist[(size_t)ch * NB + i] = v;
            if (v) atomicAdd(&total[i], v);
        }
    } else if (blk < PB_BT1) {                 // cast x -> bf16 + fp8
        int i = (blk - PB_CAST) * 256 + tid;
        float4 v = *reinterpret_cast<const float4*>(x + (size_t)i * 4);
        ushort4 o;
        o.x = f2bf(v.x); o.y = f2bf(v.y); o.z = f2bf(v.z); o.w = f2bf(v.w);
        *reinterpret_cast<ushort4*>(xb + (size_t)i * 4) = o;
        int r = __builtin_amdgcn_cvt_pk_fp8_f32(v.x, v.y, 0, false);
        r = __builtin_amdgcn_cvt_pk_fp8_f32(v.z, v.w, r, true);
        xq[i] = (unsigned)r;
    } else if (blk < PB_BT2) {                 // Bt1[n][k]
        int idx = (blk - PB_BT1) * 256 + tid;
        int n = idx >> 8, k = idx & 255;
        float v = (k < 128) ? Wl1[(size_t)k * NH + n] : Wr1[(size_t)(k - 128) * NH + n];
        Bt1[idx] = f2bf(v);
    } else {                                   // Bt2[n][k]
        int idx = (blk - PB_BT2) * 256 + tid;
        int n = idx >> 8, k = idx & 255;
        float v = 0.f;
        if (n < 47) v = Wl2[(size_t)k * NC + n];
        else if (n >= 48 && n < 95) v = Wr2[(size_t)k * NC + (n - 48)];
        Bt2[idx] = f2bf(v);
    }
}

// ---------------- fused scan + per-bucket column scan ----------------

__global__ __launch_bounds__(64) void scancol_k(const int* __restrict__ chunk_hist,
                                                const int* __restrict__ total,
                                                int* __restrict__ bucket_base,
                                                int* __restrict__ chunk_off) {
    int b = blockIdx.x;
    int lane = threadIdx.x;
    int base = 0;
    for (int i0 = 0; i0 < NB; i0 += 64) {
        int i = i0 + lane;
        base += (i < b) ? total[i] : 0;
    }
    #pragma unroll
    for (int off = 1; off < 64; off <<= 1)
        base += __shfl_xor(base, off);
    if (lane == 0) bucket_base[b] = base;
    int run = base;
    for (int c0 = 0; c0 < NCH; c0 += 64) {
        int c = c0 + lane;
        int v = (c < NCH) ? chunk_hist[(size_t)c * NB + b] : 0;
        int s = v;
        #pragma unroll
        for (int off = 1; off < 64; off <<= 1) {
            int t = __shfl_up(s, off);
            if (lane >= off) s += t;
        }
        if (c < NCH) chunk_off[(size_t)c * NB + b] = run + s - v;
        run += __shfl(s, 63);
    }
}

__global__ __launch_bounds__(256) void scatter2_k(const int* __restrict__ src,
                                                  const int* __restrict__ dst,
                                                  const int* __restrict__ chunk_off,
                                                  unsigned* __restrict__ ebuf) {
    __shared__ int cur[NB];
    int tid = threadIdx.x, ch = blockIdx.x;
    for (int i = tid; i < NB; i += 256)
        cur[i] = chunk_off[(size_t)ch * NB + i];
    __syncthreads();
    int e0 = ch * CH;
    int e1 = min(e0 + CH, NE);
    for (int e = e0 + tid; e < e1; e += 256) {
        int d = dst[e];
        int b = d >> 8;
        int p = atomicAdd(&cur[b], 1);
        ebuf[p] = ((unsigned)(d & 255) << 24) | (unsigned)src[e];
    }
}

__global__ __launch_bounds__(256) void build_csr_k(const unsigned* __restrict__ ebuf,
                                                   const int* __restrict__ bucket_base,
                                                   const int* __restrict__ bucket_cnt,
                                                   int* __restrict__ row_start,
                                                   int* __restrict__ deg,
                                                   float* __restrict__ inv_deg,
                                                   int* __restrict__ csr_src) {
    __shared__ int s[256];
    __shared__ int cursor[256];
    int tid = threadIdx.x;
    int b = blockIdx.x;
    int lo = b << 8;
    int ebase = bucket_base[b];
    int ne = bucket_cnt[b];

    s[tid] = 0;
    __syncthreads();
    for (int e = tid; e < ne; e += 256)
        atomicAdd(&s[ebuf[ebase + e] >> 24], 1);
    __syncthreads();
    int v = s[tid];
    __syncthreads();
    for (int off = 1; off < 256; off <<= 1) {
        int t = (tid >= off) ? s[tid - off] : 0;
        __syncthreads();
        s[tid] += t;
        __syncthreads();
    }
    int excl = s[tid] - v;
    int node = lo + tid;
    if (node < NN) {
        row_start[node] = ebase + excl;
        deg[node] = v;
        inv_deg[node] = 1.0f / (float)(v > 1 ? v : 1);
    }
    cursor[tid] = ebase + excl;
    __syncthreads();
    for (int e = tid; e < ne; e += 256) {
        unsigned u = ebuf[ebase + e];
        int p = atomicAdd(&cursor[u >> 24], 1);
        csr_src[p] = (int)(u & 0xFFFFFFu);
    }
}

// ---------------- aggregation: node per 16-lane group, 8 rows in flight per group ----------------

// fp8 x-gather: row = 128B = 16 lanes x uint2.
__global__ __launch_bounds__(256) void agg_mean_128q_k(const unsigned* __restrict__ xq,
                                                       const int* __restrict__ csr_src,
                                                       const int* __restrict__ row_start,
                                                       const int* __restrict__ deg,
                                                       const float* __restrict__ inv_deg,
                                                       unsigned short* __restrict__ mean1) {
    int node = blockIdx.x * 16 + (threadIdx.x >> 4);
    int l16 = threadIdx.x & 15;
    if (node >= NN) return;
    int s0 = row_start[node];
    int d  = deg[node];
    f32x2 acc[4];
    #pragma unroll
    for (int k = 0; k < 4; ++k) acc[k] = f32x2{0.f, 0.f};
    int j = 0;
    for (; j + 7 < d; j += 8) {                 // 8 rows in flight per group
        uint2 w[8];
        #pragma unroll
        for (int r = 0; r < 8; ++r) {
            int s = csr_src[s0 + j + r];
            w[r] = *reinterpret_cast<const uint2*>(xq + (size_t)s * 32 + l16 * 2);
        }
        #pragma unroll
        for (int r = 0; r < 8; ++r) {
            acc[0] += __builtin_amdgcn_cvt_pk_f32_fp8((int)w[r].x, false);
            acc[1] += __builtin_amdgcn_cvt_pk_f32_fp8((int)w[r].x, true);
            acc[2] += __builtin_amdgcn_cvt_pk_f32_fp8((int)w[r].y, false);
            acc[3] += __builtin_amdgcn_cvt_pk_f32_fp8((int)w[r].y, true);
        }
    }
    for (; j + 3 < d; j += 4) {                 // 4 rows
        uint2 w[4];
        #pragma unroll
        for (int r = 0; r < 4; ++r) {
            int s = csr_src[s0 + j + r];
            w[r] = *reinterpret_cast<const uint2*>(xq + (size_t)s * 32 + l16 * 2);
        }
        #pragma unroll
        for (int r = 0; r < 4; ++r) {
            acc[0] += __builtin_amdgcn_cvt_pk_f32_fp8((int)w[r].x, false);
            acc[1] += __builtin_amdgcn_cvt_pk_f32_fp8((int)w[r].x, true);
            acc[2] += __builtin_amdgcn_cvt_pk_f32_fp8((int)w[r].y, false);
            acc[3] += __builtin_amdgcn_cvt_pk_f32_fp8((int)w[r].y, true);
        }
    }
    for (; j < d; ++j) {
        int s = csr_src[s0 + j];
        uint2 w = *reinterpret_cast<const uint2*>(xq + (size_t)s * 32 + l16 * 2);
        acc[0] += __builtin_amdgcn_cvt_pk_f32_fp8((int)w.x, false);
        acc[1] += __builtin_amdgcn_cvt_pk_f32_fp8((int)w.x, true);
        acc[2] += __builtin_amdgcn_cvt_pk_f32_fp8((int)w.y, false);
        acc[3] += __builtin_amdgcn_cvt_pk_f32_fp8((int)w.y, true);
    }
    float inv = inv_deg[node];
    bf16x8 o;
    #pragma unroll
    for (int k = 0; k < 4; ++k) {
        o[k * 2]     = (short)f2bf(acc[k].x * inv);
        o[k * 2 + 1] = (short)f2bf(acc[k].y * inv);
    }
    *reinterpret_cast<bf16x8*>(mean1 + (size_t)node * NF + l16 * 8) = o;
}

// fp8 t-gather: row = 64B = 16 lanes x dword.
__global__ __launch_bounds__(256) void agg_mean_47q_add_k(const unsigned* __restrict__ tq,
                                                          const int* __restrict__ csr_src,
                                                          const int* __restrict__ row_start,
                                                          const int* __restrict__ deg,
                                                          const float* __restrict__ inv_deg,
                                                          float* __restrict__ out) {
    int node = blockIdx.x * 16 + (threadIdx.x >> 4);
    int l16 = threadIdx.x & 15;
    if (node >= NN) return;
    int s0 = row_start[node];
    int d  = deg[node];
    f32x2 a01 = {0.f, 0.f}, a23 = {0.f, 0.f};
    int j = 0;
    for (; j + 7 < d; j += 8) {                 // 8 rows in flight per group
        unsigned w[8];
        #pragma unroll
        for (int r = 0; r < 8; ++r) {
            int s = csr_src[s0 + j + r];
            w[r] = tq[(size_t)s * 16 + l16];
        }
        #pragma unroll
        for (int r = 0; r < 8; ++r) {
            a01 += __builtin_amdgcn_cvt_pk_f32_fp8((int)w[r], false);
            a23 += __builtin_amdgcn_cvt_pk_f32_fp8((int)w[r], true);
        }
    }
    for (; j + 3 < d; j += 4) {
        unsigned w[4];
        #pragma unroll
        for (int r = 0; r < 4; ++r) {
            int s = csr_src[s0 + j + r];
            w[r] = tq[(size_t)s * 16 + l16];
        }
        #pragma unroll
        for (int r = 0; r < 4; ++r) {
            a01 += __builtin_amdgcn_cvt_pk_f32_fp8((int)w[r], false);
            a23 += __builtin_amdgcn_cvt_pk_f32_fp8((int)w[r], true);
        }
    }
    for (; j < d; ++j) {
        int s = csr_src[s0 + j];
        unsigned w = tq[(size_t)s * 16 + l16];
        a01 += __builtin_amdgcn_cvt_pk_f32_fp8((int)w, false);
        a23 += __builtin_amdgcn_cvt_pk_f32_fp8((int)w, true);
    }
    float inv = inv_deg[node];
    int c0 = l16 * 4;
    float vals[4] = {a01.x, a01.y, a23.x, a23.y};
    #pragma unroll
    for (int m = 0; m < 4; ++m) {
        int col = c0 + m;
        if (col < NC) {
            size_t o = (size_t)node * NC + col;
            out[o] += vals[m] * inv;
        }
    }
}

// ---------------- fused GEMM12: BM=64, 4 waves, 40 KB LDS -> 4 blocks/CU ----------------
// gemm1: 4 waves, each 64x64 (wc=wid), BK=32, 2-buffer gload_lds staging.
// gemm2: waves 2x2 (32x48 each), A from Hs, B from L2-hot Bt2.
// LDS = max(As*2+Bs*2 = 40 KB, Hs = 32 KB) = 40 KB.

__global__ __launch_bounds__(256, 4) void gemm12_k(const unsigned short* __restrict__ mean1,
                                                   const unsigned short* __restrict__ xb,
                                                   const unsigned short* __restrict__ Bt1,
                                                   const float* __restrict__ b1,
                                                   const unsigned short* __restrict__ Bt2,
                                                   const float* __restrict__ b2,
                                                   unsigned char* __restrict__ tq,
                                                   float* __restrict__ out) {
    __shared__ __align__(16) union SM {
        struct { short As[2][64 * 32]; short Bs[2][256 * 32]; } g;   // 40 KB, gemm1 only
        unsigned short Hs[64 * 256];                                  // 32 KB, after gemm1
    } sm;
    const int tid = threadIdx.x;
    const int row0 = blockIdx.x * 64;
    const int lane = tid & 63;
    const int wid = tid >> 6;                    // 0..3
    const int r15 = lane & 15;
    const int kg = lane >> 4;                    // 0..3
    const int swz = (kg ^ ((lane >> 1) & 3)) & 3;

    // ---- gemm1: wave wc=wid covers cols wc*64..wc*64+63, all 64 rows ----
    const int wc = wid;
    f32x4 acc[4][4];
    #pragma unroll
    for (int i = 0; i < 4; ++i)
        #pragma unroll
        for (int j = 0; j < 4; ++j)
            acc[i][j] = f32x4{0.f, 0.f, 0.f, 0.f};

    auto stage = [&](int buf, int kt) {
        {   // A: 64 rows x 4 k-groups = 256 chunks, 1/thread; source-group swizzled
            int row = tid >> 2, g = tid & 3;
            int grow = row0 + row;
            if (grow >= NN) grow = NN - 1;       // clamp; outputs guarded later
            int gs = g ^ ((row >> 1) & 3);
            const unsigned short* asrc = (kt < 128) ? mean1 : xb;
            gload16(asrc + (size_t)grow * NF + (kt & 127) + gs * 8, &sm.g.As[buf][tid * 8]);
        }
        #pragma unroll
        for (int i = 0; i < 4; ++i) {            // B: 256 rows x 4 groups = 1024 chunks
            int c = tid + i * 256;
            int rn = c >> 2, g = c & 3;
            int gs = g ^ ((rn >> 1) & 3);
            gload16(Bt1 + (size_t)rn * 256 + kt + gs * 8, &sm.g.Bs[buf][c * 8]);
        }
    };
    auto compute = [&](int buf) {
        bf16x8 a[4], b[4];
        #pragma unroll
        for (int mi = 0; mi < 4; ++mi)
            a[mi] = *reinterpret_cast<const bf16x8*>(&sm.g.As[buf][(mi * 16 + r15) * 32 + swz * 8]);
        #pragma unroll
        for (int ni = 0; ni < 4; ++ni)
            b[ni] = *reinterpret_cast<const bf16x8*>(&sm.g.Bs[buf][(wc * 64 + ni * 16 + r15) * 32 + swz * 8]);
        #pragma unroll
        for (int mi = 0; mi < 4; ++mi)
            #pragma unroll
            for (int ni = 0; ni < 4; ++ni)
                acc[mi][ni] = __builtin_amdgcn_mfma_f32_16x16x32_bf16(a[mi], b[ni], acc[mi][ni], 0, 0, 0);
    };

    stage(0, 0);
    __syncthreads();
    int cur = 0;
    #pragma unroll 1
    for (int ks = 0; ks < 8; ++ks) {
        if (ks + 1 < 8) stage(cur ^ 1, (ks + 1) * 32);
        compute(cur);
        __syncthreads();
        cur ^= 1;
    }
    // all gemm1 LDS reads done -> Hs overwrite safe

    // h -> LDS (relu+bias, bf16, swizzled)
    #pragma unroll
    for (int ni = 0; ni < 4; ++ni) {
        int col = wc * 64 + ni * 16 + r15;
        float bias = b1[col];
        int kgrp = col >> 3, within = col & 7;
        #pragma unroll
        for (int mi = 0; mi < 4; ++mi) {
            int rbase = mi * 16 + kg * 4;
            f32x4 c = acc[mi][ni];
            #pragma unroll
            for (int q = 0; q < 4; ++q) {
                int row = rbase + q;
                float v = fmaxf(c[q] + bias, 0.f);
                sm.Hs[row * 256 + (kgrp ^ (row & 31)) * 8 + within] = f2bf(v);
            }
        }
    }
    __syncthreads();

    // ---- gemm2: waves 2x2 (rows 32, cols 48 each); A from Hs, B from Bt2 ----
    const int wr2 = wid >> 1, wc2 = wid & 1;
    f32x4 acc2[2][3];
    #pragma unroll
    for (int i = 0; i < 2; ++i)
        #pragma unroll
        for (int j = 0; j < 3; ++j)
            acc2[i][j] = f32x4{0.f, 0.f, 0.f, 0.f};

    #pragma unroll
    for (int kt = 0; kt < 256; kt += 32) {
        bf16x8 a2[2], b2f[3];
        #pragma unroll
        for (int mi = 0; mi < 2; ++mi) {
            int row = wr2 * 32 + mi * 16 + r15;
            int kgrp = (kt >> 3) + kg;
            a2[mi] = *reinterpret_cast<const bf16x8*>(&sm.Hs[row * 256 + (kgrp ^ (row & 31)) * 8]);
        }
        #pragma unroll
        for (int ni = 0; ni < 3; ++ni) {
            int n = wc2 * 48 + ni * 16 + r15;
            b2f[ni] = *reinterpret_cast<const bf16x8*>(Bt2 + (size_t)n * 256 + kt + kg * 8);
        }
        #pragma unroll
        for (int mi = 0; mi < 2; ++mi)
            #pragma unroll
            for (int ni = 0; ni < 3; ++ni)
                acc2[mi][ni] = __builtin_amdgcn_mfma_f32_16x16x32_bf16(a2[mi], b2f[ni], acc2[mi][ni], 0, 0, 0);
    }

    #pragma unroll
    for (int ni = 0; ni < 3; ++ni) {
        int col = wc2 * 48 + ni * 16 + r15;      // 0..95
        float bias = (col >= 48 && col < 95) ? b2[col - 48] : 0.f;
        #pragma unroll
        for (int mi = 0; mi < 2; ++mi) {
            int rbase = row0 + wr2 * 32 + mi * 16 + kg * 4;
            f32x4 c = acc2[mi][ni];
            #pragma unroll
            for (int q = 0; q < 4; ++q) {
                int row = rbase + q;
                if (row < NN) {
                    if (col < 47) {
                        int p = __builtin_amdgcn_cvt_pk_fp8_f32(c[q], c[q], 0, false);
                        tq[(size_t)row * 64 + col] = (unsigned char)(p & 0xFF);
                    } else if (col >= 48 && col < 95) {
                        out[(size_t)row * NC + (col - 48)] = c[q] + bias;
                    }
                }
            }
        }
    }
}

// ---------------- launch ----------------

extern "C" void kernel_launch(void* const* d_in, const int* in_sizes, int n_in,
                              void* d_out, int out_size, void* d_ws, size_t ws_size,
                              hipStream_t stream) {
    const float* x    = (const float*)d_in[0];
    const int*   eidx = (const int*)d_in[1];
    const float* Wl1  = (const float*)d_in[2];
    const float* Wr1  = (const float*)d_in[3];
    const float* b1   = (const float*)d_in[4];
    const float* Wl2  = (const float*)d_in[5];
    const float* Wr2  = (const float*)d_in[6];
    const float* b2   = (const float*)d_in[7];
    float* out = (float*)d_out;

    const int* src = eidx;
    const int* dst = eidx + NE;

    size_t off = 0;
    auto alloc = [&](size_t bytes) -> void* {
        void* p = (char*)d_ws + off;
        off += (bytes + 511) & ~(size_t)511;
        return p;
    };
    int*            deg        = (int*)alloc((size_t)NN * 4);
    int*            row_start  = (int*)alloc((size_t)NN * 4);
    float*          inv_deg    = (float*)alloc((size_t)NN * 4);
    int*            csr_src    = (int*)alloc((size_t)NE * 4);
    unsigned*       ebuf       = (unsigned*)alloc((size_t)NE * 4);
    int*            chunk_hist = (int*)alloc((size_t)NCH * NB * 4);
    int*            chunk_off  = (int*)alloc((size_t)NCH * NB * 4);
    int*            bkt_cnt    = (int*)alloc((size_t)NB * 4);
    int*            bkt_base   = (int*)alloc((size_t)NB * 4);
    unsigned short* xb         = (unsigned short*)alloc((size_t)NN * NF * 2);
    unsigned*       xq         = (unsigned*)alloc((size_t)NN * NF);       // fp8 x, 32 words/row
    unsigned short* mean1      = (unsigned short*)alloc((size_t)NN * NF * 2);
    unsigned char*  tq         = (unsigned char*)alloc((size_t)NN * 64);  // fp8 t, 64B rows
    unsigned short* Bt1        = (unsigned short*)alloc((size_t)256 * 256 * 2);
    unsigned short* Bt2        = (unsigned short*)alloc((size_t)96 * 256 * 2);
    (void)ws_size; (void)n_in; (void)in_sizes; (void)out_size;

    hipMemsetAsync(bkt_cnt, 0, (size_t)NB * 4, stream);
    prep_k<<<PB_END, 256, 0, stream>>>(dst, chunk_hist, bkt_cnt,
                                       x, xb, xq, Wl1, Wr1, Bt1, Wl2, Wr2, Bt2);
    scancol_k<<<NB, 64, 0, stream>>>(chunk_hist, bkt_cnt, bkt_base, chunk_off);
    scatter2_k<<<NCH, 256, 0, stream>>>(src, dst, chunk_off, ebuf);
    build_csr_k<<<NB, 256, 0, stream>>>(ebuf, bkt_base, bkt_cnt,
                                        row_start, deg, inv_deg, csr_src);

    agg_mean_128q_k<<<(NN + 15) / 16, 256, 0, stream>>>(xq, csr_src, row_start, deg, inv_deg, mean1);

    gemm12_k<<<(NN + 63) / 64, 256, 0, stream>>>(mean1, xb, Bt1, b1, Bt2, b2, tq, out);

    agg_mean_47q_add_k<<<(NN + 15) / 16, 256, 0, stream>>>((const unsigned*)tq, csr_src, row_start, deg, inv_deg, out);
}